// Round 1
// baseline (803.014 us; speedup 1.0000x reference)
//
#include <hip/hip_runtime.h>

typedef float v2f __attribute__((ext_vector_type(2)));
typedef float v4f __attribute__((ext_vector_type(4)));

#define TPB 256

// One thread handles samples g and g+halfB. Weights live in LDS, transposed to
// [input][neuron] so the unrolled neuron loops read contiguous float4s
// (wave-uniform address -> LDS broadcast, no bank conflicts).
__global__ __launch_bounds__(TPB, 2)
void nnue_kernel(const float* __restrict__ pov,
                 const float* __restrict__ white,
                 const float* __restrict__ black,
                 const float* __restrict__ Ww, const float* __restrict__ bwv,
                 const float* __restrict__ Wb, const float* __restrict__ bbv,
                 const float* __restrict__ W0, const float* __restrict__ b0v,
                 const float* __restrict__ W1, const float* __restrict__ b1v,
                 const float* __restrict__ W2, const float* __restrict__ b2v,
                 float* __restrict__ out, int halfB)
{
    // per k (0..48): [Ww[:,k] (32) | Ww[:,49+k] (32) | Wb[:,k] (32) | Wb[:,49+k] (32)]
    __shared__ __align__(16) float sF[49 * 128];
    __shared__ __align__(16) float sW0[64 * 32];   // sW0[i*32+j] = W0[j,i]
    __shared__ __align__(16) float sW1[32 * 32];   // sW1[i*32+j] = W1[j,i]
    __shared__ __align__(16) float sW2[64];
    __shared__ __align__(16) float sBw[32];
    __shared__ __align__(16) float sBb[32];
    __shared__ __align__(16) float sB0[32];
    __shared__ __align__(16) float sB1[32];
    __shared__ float sB2;

    const int tid = threadIdx.x;

    for (int idx = tid; idx < 49 * 128; idx += TPB) {
        int k = idx >> 7;
        int r = idx & 127;
        int sel = r >> 5;
        int j = r & 31;
        float v;
        if      (sel == 0) v = Ww[j * 98 + k];
        else if (sel == 1) v = Ww[j * 98 + 49 + k];
        else if (sel == 2) v = Wb[j * 98 + k];
        else               v = Wb[j * 98 + 49 + k];
        sF[idx] = v;
    }
    for (int idx = tid; idx < 64 * 32; idx += TPB) {
        int i = idx >> 5, j = idx & 31;
        sW0[idx] = W0[j * 64 + i];
    }
    for (int idx = tid; idx < 32 * 32; idx += TPB) {
        int i = idx >> 5, j = idx & 31;
        sW1[idx] = W1[j * 32 + i];
    }
    if (tid < 64) sW2[tid] = W2[tid];
    if (tid < 32) {
        sBw[tid] = bwv[tid];
        sBb[tid] = bbv[tid];
        sB0[tid] = b0v[tid];
        sB1[tid] = b1v[tid];
    }
    if (tid == 0) sB2 = b2v[0];
    __syncthreads();

    const int g = blockIdx.x * TPB + tid;
    if (g >= halfB) return;                    // no barriers after this point
    const int s1 = g + halfB;

    const float* wr0 = white + (size_t)g  * 49;
    const float* wr1 = white + (size_t)s1 * 49;
    const float* br0 = black + (size_t)g  * 49;
    const float* br1 = black + (size_t)s1 * 49;

    // ---- feature transform: w_ = [white,black]@Ww^T + bw ; b_ = [black,white]@Wb^T + bb
    v2f wacc[2][16], bacc[2][16];              // j-pairs, 2 samples
    {
        const v2f* bwp = (const v2f*)sBw;
        const v2f* bbp = (const v2f*)sBb;
        #pragma unroll
        for (int p = 0; p < 16; ++p) {
            v2f w = bwp[p], b = bbp[p];
            wacc[0][p] = w; wacc[1][p] = w;
            bacc[0][p] = b; bacc[1][p] = b;
        }
    }

    const v4f* vF = (const v4f*)sF;

    #pragma unroll 1
    for (int kc = 0; kc < 49; kc += 7) {
        float ws[2][7], bs[2][7];
        #pragma unroll
        for (int t = 0; t < 7; ++t) {
            ws[0][t] = wr0[kc + t];
            ws[1][t] = wr1[kc + t];
            bs[0][t] = br0[kc + t];
            bs[1][t] = br1[kc + t];
        }
        #pragma unroll
        for (int t = 0; t < 7; ++t) {
            const int k = kc + t;
            const v4f* f = vF + k * 32;
            #pragma unroll
            for (int q = 0; q < 8; ++q) {
                v4f A  = f[q];
                v4f Bm = f[8 + q];
                v4f C  = f[16 + q];
                v4f D  = f[24 + q];
                v2f A0 = {A[0],  A[1]},  A1 = {A[2],  A[3]};
                v2f B0 = {Bm[0], Bm[1]}, B1 = {Bm[2], Bm[3]};
                v2f C0 = {C[0],  C[1]},  C1 = {C[2],  C[3]};
                v2f D0 = {D[0],  D[1]},  D1 = {D[2],  D[3]};
                #pragma unroll
                for (int s = 0; s < 2; ++s) {
                    v2f wv = {ws[s][t], ws[s][t]};
                    v2f bv = {bs[s][t], bs[s][t]};
                    wacc[s][2*q]   = __builtin_elementwise_fma(wv, A0, __builtin_elementwise_fma(bv, B0, wacc[s][2*q]));
                    wacc[s][2*q+1] = __builtin_elementwise_fma(wv, A1, __builtin_elementwise_fma(bv, B1, wacc[s][2*q+1]));
                    bacc[s][2*q]   = __builtin_elementwise_fma(bv, C0, __builtin_elementwise_fma(wv, D0, bacc[s][2*q]));
                    bacc[s][2*q+1] = __builtin_elementwise_fma(bv, C1, __builtin_elementwise_fma(wv, D1, bacc[s][2*q+1]));
                }
            }
        }
    }

    // ---- pov blend + relu: base[0:32]=relu(p*w_+(1-p)*b_)  base[32:64]=relu(p*b_+(1-p)*w_)
    const v2f zero = {0.f, 0.f};
    float pv[2] = {pov[g], pov[s1]};
    #pragma unroll
    for (int s = 0; s < 2; ++s) {
        v2f p = {pv[s], pv[s]};
        #pragma unroll
        for (int pr = 0; pr < 16; ++pr) {
            v2f w = wacc[s][pr], b = bacc[s][pr];
            v2f d = w - b;
            v2f e0 = __builtin_elementwise_fma(p, d, b);   // p*w + (1-p)*b
            v2f e1 = w - p * d;                             // p*b + (1-p)*w
            wacc[s][pr] = __builtin_elementwise_max(e0, zero);  // base[0:32]
            bacc[s][pr] = __builtin_elementwise_max(e1, zero);  // base[32:64]
        }
    }

    // ---- layer0: x0 = relu(base @ W0^T + b0)
    v2f x0[2][16];
    {
        const v2f* b0p = (const v2f*)sB0;
        #pragma unroll
        for (int m = 0; m < 16; ++m) { x0[0][m] = b0p[m]; x0[1][m] = b0p[m]; }
    }
    {
        const v4f* vW0 = (const v4f*)sW0;
        #pragma unroll
        for (int i = 0; i < 64; ++i) {
            float v0, v1;
            if (i < 32) { v0 = wacc[0][i >> 1][i & 1];        v1 = wacc[1][i >> 1][i & 1]; }
            else        { v0 = bacc[0][(i - 32) >> 1][i & 1]; v1 = bacc[1][(i - 32) >> 1][i & 1]; }
            v2f s0v = {v0, v0}, s1v = {v1, v1};
            const v4f* r = vW0 + i * 8;
            #pragma unroll
            for (int q = 0; q < 8; ++q) {
                v4f w = r[q];
                v2f w0 = {w[0], w[1]}, w1 = {w[2], w[3]};
                x0[0][2*q]   = __builtin_elementwise_fma(s0v, w0, x0[0][2*q]);
                x0[0][2*q+1] = __builtin_elementwise_fma(s0v, w1, x0[0][2*q+1]);
                x0[1][2*q]   = __builtin_elementwise_fma(s1v, w0, x0[1][2*q]);
                x0[1][2*q+1] = __builtin_elementwise_fma(s1v, w1, x0[1][2*q+1]);
            }
        }
        #pragma unroll
        for (int s = 0; s < 2; ++s)
            #pragma unroll
            for (int m = 0; m < 16; ++m)
                x0[s][m] = __builtin_elementwise_max(x0[s][m], zero);
    }

    // ---- layer1: x1 = x0 @ W1^T + b1   (relu folded into final dot)
    v2f x1[2][16];
    {
        const v2f* b1p = (const v2f*)sB1;
        #pragma unroll
        for (int m = 0; m < 16; ++m) { x1[0][m] = b1p[m]; x1[1][m] = b1p[m]; }
        const v4f* vW1 = (const v4f*)sW1;
        #pragma unroll
        for (int i = 0; i < 32; ++i) {
            float v0 = x0[0][i >> 1][i & 1];
            float v1 = x0[1][i >> 1][i & 1];
            v2f s0v = {v0, v0}, s1v = {v1, v1};
            const v4f* r = vW1 + i * 8;
            #pragma unroll
            for (int q = 0; q < 8; ++q) {
                v4f w = r[q];
                v2f w0 = {w[0], w[1]}, w1 = {w[2], w[3]};
                x1[0][2*q]   = __builtin_elementwise_fma(s0v, w0, x1[0][2*q]);
                x1[0][2*q+1] = __builtin_elementwise_fma(s0v, w1, x1[0][2*q+1]);
                x1[1][2*q]   = __builtin_elementwise_fma(s1v, w0, x1[1][2*q]);
                x1[1][2*q+1] = __builtin_elementwise_fma(s1v, w1, x1[1][2*q+1]);
            }
        }
    }

    // ---- output: out = x0·W2[0:32] + relu(x1)·W2[32:64] + b2
    v2f acc0 = zero, acc1 = zero;
    {
        const v2f* vW2 = (const v2f*)sW2;
        #pragma unroll
        for (int m = 0; m < 16; ++m) {
            v2f w_lo = vW2[m];
            v2f w_hi = vW2[16 + m];
            acc0 = __builtin_elementwise_fma(x0[0][m], w_lo, acc0);
            acc1 = __builtin_elementwise_fma(x0[1][m], w_lo, acc1);
            v2f r0 = __builtin_elementwise_max(x1[0][m], zero);
            v2f r1 = __builtin_elementwise_max(x1[1][m], zero);
            acc0 = __builtin_elementwise_fma(r0, w_hi, acc0);
            acc1 = __builtin_elementwise_fma(r1, w_hi, acc1);
        }
    }
    float b2s = sB2;
    out[g]  = b2s + acc0[0] + acc0[1];
    out[s1] = b2s + acc1[0] + acc1[1];
}

extern "C" void kernel_launch(void* const* d_in, const int* in_sizes, int n_in,
                              void* d_out, int out_size, void* d_ws, size_t ws_size,
                              hipStream_t stream)
{
    const float* pov   = (const float*)d_in[0];
    const float* white = (const float*)d_in[1];
    const float* black = (const float*)d_in[2];
    const float* Ww = (const float*)d_in[3];
    const float* bw = (const float*)d_in[4];
    const float* Wb = (const float*)d_in[5];
    const float* bb = (const float*)d_in[6];
    const float* W0 = (const float*)d_in[7];
    const float* b0 = (const float*)d_in[8];
    const float* W1 = (const float*)d_in[9];
    const float* b1 = (const float*)d_in[10];
    const float* W2 = (const float*)d_in[11];
    const float* b2 = (const float*)d_in[12];
    float* out = (float*)d_out;

    const int B = in_sizes[0];
    const int halfB = B / 2;
    const int nblocks = (halfB + TPB - 1) / TPB;
    hipLaunchKernelGGL(nnue_kernel, dim3(nblocks), dim3(TPB), 0, stream,
                       pov, white, black, Ww, bw, Wb, bb, W0, b0, W1, b1, W2, b2,
                       out, halfB);
}

// Round 2
// 548.893 us; speedup vs baseline: 1.4630x; 1.4630x over previous
//
#include <hip/hip_runtime.h>

typedef short bf8 __attribute__((ext_vector_type(8)));   // 8 bf16 lanes-worth (4 VGPRs)
typedef float f4 __attribute__((ext_vector_type(4)));
typedef unsigned int u32;
typedef u32 u32x4 __attribute__((ext_vector_type(4)));

#define TPB 256

__device__ __forceinline__ unsigned short bf16_rne(float x) {
    u32 u = __float_as_uint(x);
    u32 r = u + 0x7FFFu + ((u >> 16) & 1u);
    return (unsigned short)(r >> 16);
}

__device__ __forceinline__ f4 mfma16(bf8 a, bf8 b, f4 c) {
    return __builtin_amdgcn_mfma_f32_16x16x32_bf16(a, b, c, 0, 0, 0);
}

// split 8 fp32 -> hi bf16 frag + lo bf16 frag (truncation split: x = h + l to ~2^-16 rel)
__device__ __forceinline__ void cvt_split8(const float* a, bf8& H, bf8& L) {
    u32 hd[4], ld[4];
#pragma unroll
    for (int i = 0; i < 4; ++i) {
        u32 b0 = __float_as_uint(a[2*i]);
        u32 b1 = __float_as_uint(a[2*i+1]);
        u32 h0 = b0 & 0xFFFF0000u;
        u32 h1 = b1 & 0xFFFF0000u;
        float l0 = a[2*i]   - __uint_as_float(h0);
        float l1 = a[2*i+1] - __uint_as_float(h1);
        hd[i] = (h0 >> 16) | h1;
        ld[i] = (__float_as_uint(l0) >> 16) | (__float_as_uint(l1) & 0xFFFF0000u);
    }
    u32x4 hv = {hd[0], hd[1], hd[2], hd[3]};
    u32x4 lv = {ld[0], ld[1], ld[2], ld[3]};
    H = __builtin_bit_cast(bf8, hv);
    L = __builtin_bit_cast(bf8, lv);
}

// Workgroup = 4 waves, each wave owns 32 samples (2 M-tiles of 16).
// Weight B-fragments staged once per WG into LDS as lane-indexed frag dumps:
//   pair p in [0,22): planes 2p (hi) and 2p+1 (lo), each 256 dwords;
//   lane reads its 16B at plane*1024 + lane*16  -> conflict-free ds_read_b128.
//   FT pairs:  p = (ks*2+mat)*2 + t   (ks<4, mat: 0=Ww,1=Wb-rotated, t = n-tile)
//   L0 pairs:  p = 16 + ks*2 + t      (ks<2)
//   L1 pairs:  p = 20 + t
__global__ __launch_bounds__(TPB, 2)
void nnue_mfma(const float* __restrict__ pov, const float* __restrict__ white,
               const float* __restrict__ black,
               const float* __restrict__ Ww, const float* __restrict__ bwv,
               const float* __restrict__ Wb, const float* __restrict__ bbv,
               const float* __restrict__ W0, const float* __restrict__ b0v,
               const float* __restrict__ W1, const float* __restrict__ b1v,
               const float* __restrict__ W2, const float* __restrict__ b2v,
               float* __restrict__ out, int B)
{
    __shared__ __align__(16) u32 sDump[11264];               // 44 KB frag dumps
    __shared__ __align__(16) float sW2r[64];                 // [n][4] = W2[4t+...]
    __shared__ __align__(16) unsigned short sScrS[4 * 32 * 72]; // 18 KB activation scratch

    const int tid = threadIdx.x;

    // ---------------- weight staging ----------------
    // FT: B[k][n] = mat0: Ww[ncol][k] ; mat1: Wb[ncol][(k+49)%98] ; k>=98 -> 0
    for (int T = tid; T < 2048; T += TPB) {
        int mat = T >> 10, r = T & 1023;
        int ks = r >> 8, t = (r >> 7) & 1, kq = (r >> 5) & 3, n = (r >> 1) & 15, j0 = (r & 1) * 4;
        int ncol = t * 16 + n;
        const float* Wm = mat ? Wb : Ww;
        u32 hq[2], lq[2];
#pragma unroll
        for (int d = 0; d < 2; ++d) {
            u32 hp = 0, lp = 0;
#pragma unroll
            for (int e = 0; e < 2; ++e) {
                int k = ks * 32 + kq * 8 + j0 + d * 2 + e;
                float x = 0.f;
                if (k < 98) {
                    int kk = mat ? ((k + 49) % 98) : k;
                    x = Wm[ncol * 98 + kk];
                }
                u32 xb = __float_as_uint(x);
                u32 hb = xb & 0xFFFF0000u;
                float lf = x - __uint_as_float(hb);
                u32 lb = __float_as_uint(lf);
                hp |= (hb >> 16) << (16 * e);
                lp |= (lb >> 16) << (16 * e);
            }
            hq[d] = hp; lq[d] = lp;
        }
        int pair = (ks * 2 + mat) * 2 + t;
        int si2 = (128 * kq + 8 * n + j0) >> 1;
        sDump[(pair * 2 + 0) * 256 + si2]     = hq[0];
        sDump[(pair * 2 + 0) * 256 + si2 + 1] = hq[1];
        sDump[(pair * 2 + 1) * 256 + si2]     = lq[0];
        sDump[(pair * 2 + 1) * 256 + si2 + 1] = lq[1];
    }
    // L0: B[k][n] = W0[ncol][k], k<64
    for (int T = tid; T < 512; T += TPB) {
        int ks = (T >> 8) & 1, t = (T >> 7) & 1, kq = (T >> 5) & 3, n = (T >> 1) & 15, j0 = (T & 1) * 4;
        int ncol = t * 16 + n;
        u32 hq[2], lq[2];
#pragma unroll
        for (int d = 0; d < 2; ++d) {
            u32 hp = 0, lp = 0;
#pragma unroll
            for (int e = 0; e < 2; ++e) {
                int k = ks * 32 + kq * 8 + j0 + d * 2 + e;
                float x = W0[ncol * 64 + k];
                u32 xb = __float_as_uint(x);
                u32 hb = xb & 0xFFFF0000u;
                float lf = x - __uint_as_float(hb);
                u32 lb = __float_as_uint(lf);
                hp |= (hb >> 16) << (16 * e);
                lp |= (lb >> 16) << (16 * e);
            }
            hq[d] = hp; lq[d] = lp;
        }
        int pair = 16 + ks * 2 + t;
        int si2 = (128 * kq + 8 * n + j0) >> 1;
        sDump[(pair * 2 + 0) * 256 + si2]     = hq[0];
        sDump[(pair * 2 + 0) * 256 + si2 + 1] = hq[1];
        sDump[(pair * 2 + 1) * 256 + si2]     = lq[0];
        sDump[(pair * 2 + 1) * 256 + si2 + 1] = lq[1];
    }
    // L1: B[k][n] = W1[ncol][k], k<32
    for (int T = tid; T < 256; T += TPB) {
        int t = (T >> 7) & 1, kq = (T >> 5) & 3, n = (T >> 1) & 15, j0 = (T & 1) * 4;
        int ncol = t * 16 + n;
        u32 hq[2], lq[2];
#pragma unroll
        for (int d = 0; d < 2; ++d) {
            u32 hp = 0, lp = 0;
#pragma unroll
            for (int e = 0; e < 2; ++e) {
                int k = kq * 8 + j0 + d * 2 + e;
                float x = W1[ncol * 32 + k];
                u32 xb = __float_as_uint(x);
                u32 hb = xb & 0xFFFF0000u;
                float lf = x - __uint_as_float(hb);
                u32 lb = __float_as_uint(lf);
                hp |= (hb >> 16) << (16 * e);
                lp |= (lb >> 16) << (16 * e);
            }
            hq[d] = hp; lq[d] = lp;
        }
        int pair = 20 + t;
        int si2 = (128 * kq + 8 * n + j0) >> 1;
        sDump[(pair * 2 + 0) * 256 + si2]     = hq[0];
        sDump[(pair * 2 + 0) * 256 + si2 + 1] = hq[1];
        sDump[(pair * 2 + 1) * 256 + si2]     = lq[0];
        sDump[(pair * 2 + 1) * 256 + si2 + 1] = lq[1];
    }
    if (tid < 64) sW2r[tid] = W2[(tid & 3) * 16 + (tid >> 2)];
    __syncthreads();

    // ---------------- per-wave compute ----------------
    const int wave = tid >> 6, lane = tid & 63;
    const int n16 = lane & 15, kq = lane >> 4;
    const long long g0 = (long long)blockIdx.x * 128 + wave * 32;

    // FT accumulators [t][mt]
    f4 accw[2][2], accb[2][2];
    {
        float bw0 = bwv[n16], bw1 = bwv[16 + n16];
        float bb0 = bbv[n16], bb1 = bbv[16 + n16];
        accw[0][0] = {bw0, bw0, bw0, bw0}; accw[0][1] = accw[0][0];
        accw[1][0] = {bw1, bw1, bw1, bw1}; accw[1][1] = accw[1][0];
        accb[0][0] = {bb0, bb0, bb0, bb0}; accb[0][1] = accb[0][0];
        accb[1][0] = {bb1, bb1, bb1, bb1}; accb[1][1] = accb[1][0];
    }
    const float* wrow[2]; const float* brow[2];
#pragma unroll
    for (int mt = 0; mt < 2; ++mt) {
        long long s = g0 + mt * 16 + n16;
        if (s > (long long)B - 1) s = (long long)B - 1;
        wrow[mt] = white + s * 49;
        brow[mt] = black + s * 49;
    }

#pragma unroll
    for (int ks = 0; ks < 4; ++ks) {
        bf8 Bh[2][2], Bl[2][2];
#pragma unroll
        for (int mat = 0; mat < 2; ++mat)
#pragma unroll
            for (int t = 0; t < 2; ++t) {
                int pair = (ks * 2 + mat) * 2 + t;
                Bh[mat][t] = *(const bf8*)&sDump[(pair * 2 + 0) * 256 + lane * 4];
                Bl[mat][t] = *(const bf8*)&sDump[(pair * 2 + 1) * 256 + lane * 4];
            }
        const int base_k = ks * 32 + kq * 8;
#pragma unroll
        for (int mt = 0; mt < 2; ++mt) {
            float a[8];
#pragma unroll
            for (int j = 0; j < 8; ++j) {
                int k = base_k + j;
                float x;
                if (k < 49) x = wrow[mt][k];
                else if (k < 98) x = brow[mt][k - 49];
                else x = 0.f;
                a[j] = x;
            }
            bf8 Ah, Al;
            cvt_split8(a, Ah, Al);
#pragma unroll
            for (int t = 0; t < 2; ++t) {
                accw[t][mt] = mfma16(Ah, Bh[0][t], accw[t][mt]);
                accw[t][mt] = mfma16(Al, Bh[0][t], accw[t][mt]);
                accw[t][mt] = mfma16(Ah, Bl[0][t], accw[t][mt]);
                accb[t][mt] = mfma16(Ah, Bh[1][t], accb[t][mt]);
                accb[t][mt] = mfma16(Al, Bh[1][t], accb[t][mt]);
                accb[t][mt] = mfma16(Ah, Bl[1][t], accb[t][mt]);
            }
        }
    }

    // blend + relu -> base (bf16) into per-wave scratch rows [32][72]
    unsigned short* scr = &sScrS[wave * 32 * 72];
#pragma unroll
    for (int mt = 0; mt < 2; ++mt) {
#pragma unroll
        for (int r = 0; r < 4; ++r) {
            long long sp = g0 + mt * 16 + kq * 4 + r;
            if (sp > (long long)B - 1) sp = (long long)B - 1;
            float p = pov[sp];
            int row = mt * 16 + kq * 4 + r;
#pragma unroll
            for (int t = 0; t < 2; ++t) {
                float w = accw[t][mt][r], b = accb[t][mt][r];
                float d = w - b;
                float e0 = fmaxf(fmaf(p, d, b), 0.f);   // base[col]      (col<32)
                float e1 = fmaxf(w - p * d, 0.f);       // base[col+32]
                scr[row * 72 + t * 16 + n16]      = bf16_rne(e0);
                scr[row * 72 + 32 + t * 16 + n16] = bf16_rne(e1);
            }
        }
    }

    // L0: x0 = relu(base @ W0^T + b0)
    f4 acc0[2][2];
    {
        float c0 = b0v[n16], c1 = b0v[16 + n16];
        acc0[0][0] = {c0, c0, c0, c0}; acc0[0][1] = acc0[0][0];
        acc0[1][0] = {c1, c1, c1, c1}; acc0[1][1] = acc0[1][0];
    }
#pragma unroll
    for (int ks = 0; ks < 2; ++ks) {
        bf8 B0h[2], B0l[2];
#pragma unroll
        for (int t = 0; t < 2; ++t) {
            int pair = 16 + ks * 2 + t;
            B0h[t] = *(const bf8*)&sDump[(pair * 2 + 0) * 256 + lane * 4];
            B0l[t] = *(const bf8*)&sDump[(pair * 2 + 1) * 256 + lane * 4];
        }
#pragma unroll
        for (int mt = 0; mt < 2; ++mt) {
            bf8 A = *(const bf8*)&scr[(mt * 16 + n16) * 72 + ks * 32 + kq * 8];
#pragma unroll
            for (int t = 0; t < 2; ++t) {
                acc0[t][mt] = mfma16(A, B0h[t], acc0[t][mt]);
                acc0[t][mt] = mfma16(A, B0l[t], acc0[t][mt]);
            }
        }
    }
    // relu; keep fp32 in regs for the final dot, restage bf16 for L1
#pragma unroll
    for (int mt = 0; mt < 2; ++mt)
#pragma unroll
        for (int r = 0; r < 4; ++r)
#pragma unroll
            for (int t = 0; t < 2; ++t) {
                float v = fmaxf(acc0[t][mt][r], 0.f);
                acc0[t][mt][r] = v;
                scr[(mt * 16 + kq * 4 + r) * 72 + t * 16 + n16] = bf16_rne(v);
            }

    // L1: x1 = x0 @ W1^T + b1
    f4 acc1[2][2];
    {
        float c0 = b1v[n16], c1 = b1v[16 + n16];
        acc1[0][0] = {c0, c0, c0, c0}; acc1[0][1] = acc1[0][0];
        acc1[1][0] = {c1, c1, c1, c1}; acc1[1][1] = acc1[1][0];
    }
    {
        bf8 B1h[2], B1l[2];
#pragma unroll
        for (int t = 0; t < 2; ++t) {
            int pair = 20 + t;
            B1h[t] = *(const bf8*)&sDump[(pair * 2 + 0) * 256 + lane * 4];
            B1l[t] = *(const bf8*)&sDump[(pair * 2 + 1) * 256 + lane * 4];
        }
#pragma unroll
        for (int mt = 0; mt < 2; ++mt) {
            bf8 A = *(const bf8*)&scr[(mt * 16 + n16) * 72 + kq * 8];
#pragma unroll
            for (int t = 0; t < 2; ++t) {
                acc1[t][mt] = mfma16(A, B1h[t], acc1[t][mt]);
                acc1[t][mt] = mfma16(A, B1l[t], acc1[t][mt]);
            }
        }
    }

    // out = x0.W2[0:32] + relu(x1).W2[32:64] + b2 ; reduce over n (lane&15)
    f4 w2 = *(const f4*)&sW2r[n16 * 4];
    float b2s = b2v[0];
#pragma unroll
    for (int mt = 0; mt < 2; ++mt)
#pragma unroll
        for (int r = 0; r < 4; ++r) {
            float v = acc0[0][mt][r] * w2.x + acc0[1][mt][r] * w2.y
                    + fmaxf(acc1[0][mt][r], 0.f) * w2.z + fmaxf(acc1[1][mt][r], 0.f) * w2.w;
            v += __shfl_xor(v, 1);
            v += __shfl_xor(v, 2);
            v += __shfl_xor(v, 4);
            v += __shfl_xor(v, 8);
            if (n16 == 0) {
                long long so = g0 + mt * 16 + kq * 4 + r;
                if (so < B) out[so] = v + b2s;
            }
        }
}

extern "C" void kernel_launch(void* const* d_in, const int* in_sizes, int n_in,
                              void* d_out, int out_size, void* d_ws, size_t ws_size,
                              hipStream_t stream)
{
    const float* pov   = (const float*)d_in[0];
    const float* white = (const float*)d_in[1];
    const float* black = (const float*)d_in[2];
    const float* Ww = (const float*)d_in[3];
    const float* bw = (const float*)d_in[4];
    const float* Wb = (const float*)d_in[5];
    const float* bb = (const float*)d_in[6];
    const float* W0 = (const float*)d_in[7];
    const float* b0 = (const float*)d_in[8];
    const float* W1 = (const float*)d_in[9];
    const float* b1 = (const float*)d_in[10];
    const float* W2 = (const float*)d_in[11];
    const float* b2 = (const float*)d_in[12];
    float* out = (float*)d_out;

    const int B = in_sizes[0];
    const int nblocks = (B + 127) / 128;
    hipLaunchKernelGGL(nnue_mfma, dim3(nblocks), dim3(TPB), 0, stream,
                       pov, white, black, Ww, bw, Wb, bb, W0, b0, W1, b1, W2, b2,
                       out, B);
}

// Round 3
// 545.059 us; speedup vs baseline: 1.4733x; 1.0070x over previous
//
#include <hip/hip_runtime.h>

typedef short bf8 __attribute__((ext_vector_type(8)));   // 8 bf16 (4 VGPRs)
typedef float f4 __attribute__((ext_vector_type(4)));
typedef unsigned int u32;
typedef u32 u32x4 __attribute__((ext_vector_type(4)));
typedef u32 u32x2 __attribute__((ext_vector_type(2)));

#define TPB 256
#define WS_DW 11328   // 11264 dump dwords + 64 W2r floats

__device__ __forceinline__ f4 mfma16(bf8 a, bf8 b, f4 c) {
    return __builtin_amdgcn_mfma_f32_16x16x32_bf16(a, b, c, 0, 0, 0);
}

__device__ __forceinline__ void split1(float x, u32& h, u32& l) {
    u32 xb = __float_as_uint(x);
    u32 hb = xb & 0xFFFF0000u;
    float lf = x - __uint_as_float(hb);
    h = hb >> 16;
    l = __float_as_uint(lf) >> 16;
}

__device__ __forceinline__ u32 bf16_rne(float x) {
    u32 u = __float_as_uint(x);
    return (u + 0x7FFFu + ((u >> 16) & 1u)) >> 16;
}

__device__ __forceinline__ void cvt_split8(const float* a, bf8& H, bf8& L) {
    u32 hd[4], ld[4];
#pragma unroll
    for (int i = 0; i < 4; ++i) {
        u32 h0, l0, h1, l1;
        split1(a[2*i],   h0, l0);
        split1(a[2*i+1], h1, l1);
        hd[i] = h0 | (h1 << 16);
        ld[i] = l0 | (l1 << 16);
    }
    u32x4 hv = {hd[0], hd[1], hd[2], hd[3]};
    u32x4 lv = {ld[0], ld[1], ld[2], ld[3]};
    H = __builtin_bit_cast(bf8, hv);
    L = __builtin_bit_cast(bf8, lv);
}

// ---------------- prep: build hi/lo frag dumps once into d_ws ----------------
// FT concat layout (K=128): [white(49) | 0(15) | black(49) | 0(15)]
//   mat0 (Ww, accw): c<49 -> Ww[n][c]; 64<=c<113 -> Ww[n][c-15]; else 0
//   mat1 (Wb, accb): c<49 -> Wb[n][c+49]; 64<=c<113 -> Wb[n][c-64]; else 0
// L0/L1 use the packed-act column permutation col(k') = (k'>>5)*32 + (k'&1)*16 + ((k'>>1)&15)
__global__ void nnue_prep(const float* __restrict__ Ww, const float* __restrict__ Wb,
                          const float* __restrict__ W0, const float* __restrict__ W1,
                          const float* __restrict__ W2, u32* __restrict__ ws)
{
    int T = blockIdx.x * 256 + threadIdx.x;
    if (T < 5632) {
        int pair = T >> 8, idx = T & 255;
        int kq = idx >> 6, n = (idx >> 2) & 15, dj = idx & 3;
        u32 hp = 0, lp = 0;
#pragma unroll
        for (int e = 0; e < 2; ++e) {
            int kk = kq * 8 + dj * 2 + e;
            float x = 0.f;
            if (pair < 16) {
                int ks = pair >> 2, mat = (pair >> 1) & 1, t = pair & 1;
                int c = ks * 32 + kk;
                if (mat == 0) {
                    if (c < 49)                 x = Ww[(t*16+n)*98 + c];
                    else if (c >= 64 && c < 113) x = Ww[(t*16+n)*98 + c - 15];
                } else {
                    if (c < 49)                 x = Wb[(t*16+n)*98 + c + 49];
                    else if (c >= 64 && c < 113) x = Wb[(t*16+n)*98 + c - 64];
                }
            } else if (pair < 20) {
                int ks = (pair - 16) >> 1, t = (pair - 16) & 1;
                int k2 = ks * 32 + kk;
                int col = (k2 >> 5) * 32 + (k2 & 1) * 16 + ((k2 >> 1) & 15);
                x = W0[(t*16+n)*64 + col];
            } else {
                int t = pair - 20;
                int col = (kk & 1) * 16 + ((kk >> 1) & 15);
                x = W1[(t*16+n)*32 + col];
            }
            u32 h, l; split1(x, h, l);
            hp |= h << (16 * e);
            lp |= l << (16 * e);
        }
        ws[(pair*2+0)*256 + idx] = hp;
        ws[(pair*2+1)*256 + idx] = lp;
    } else if (T < 5696) {
        int i = T - 5632;
        ((float*)ws)[11264 + i] = W2[(i & 3) * 16 + (i >> 2)];
    }
}

// ---------------- main ----------------
// Block = 256 samples, 4 waves; wave owns 4 M-tiles (slots).
// tile(slot) = w + 4*(slot&1) + 8*(slot>>1); phase p stages rows [128p,128p+128)
// of one source flat into LDS; slots {2p,2p+1} consume it.
__global__ __launch_bounds__(TPB, 2)
void nnue_main(const float* __restrict__ pov, const float* __restrict__ white,
               const float* __restrict__ black,
               const float* __restrict__ bwv, const float* __restrict__ bbv,
               const float* __restrict__ b0v, const float* __restrict__ b1v,
               const float* __restrict__ b2v,
               const u32* __restrict__ ws, float* __restrict__ out, int B)
{
    __shared__ __align__(16) u32 sW[WS_DW];     // 45.3 KB frag dumps + W2r
    __shared__ __align__(16) u32 sBuf[8704];    // 34.8 KB: staging (6288) / act (4x2176)

    const int tid = threadIdx.x;
#pragma unroll 2
    for (int T = tid; T < WS_DW / 4; T += TPB)
        ((u32x4*)sW)[T] = ((const u32x4*)ws)[T];
    if (tid < 16) sBuf[6272 + tid] = 0;         // pad so row-127 overreads see zeros

    const int w = tid >> 6, lane = tid & 63;
    const int n16 = lane & 15, kq = lane >> 4;
    const long long G = (long long)blockIdx.x * 256;
    const long long lastq = ((long long)B * 49) / 4 - 1;

    // FT accumulators [t][slot]
    f4 accw[2][4], accb[2][4];
    {
        float c0 = bwv[n16], c1 = bwv[16+n16];
        float d0 = bbv[n16], d1 = bbv[16+n16];
#pragma unroll
        for (int s = 0; s < 4; ++s) {
            accw[0][s] = {c0,c0,c0,c0}; accw[1][s] = {c1,c1,c1,c1};
            accb[0][s] = {d0,d0,d0,d0}; accb[1][s] = {d1,d1,d1,d1};
        }
    }

    const bf8* frag = (const bf8*)sW;

#pragma unroll
    for (int p = 0; p < 2; ++p) {
#pragma unroll
        for (int src = 0; src < 2; ++src) {
            const float* sp_ = src ? black : white;
            __syncthreads();                    // prior phase reads complete
            {
                const long long q0 = ((G + 128 * p) * 49) >> 2;
                const f4* gp = (const f4*)sp_;
                for (int T = tid; T < 1568; T += TPB) {
                    long long qi = q0 + T;
                    if (qi > lastq) qi = lastq;
                    ((f4*)sBuf)[T] = gp[qi];
                }
            }
            __syncthreads();
#pragma unroll
            for (int ks2 = 0; ks2 < 2; ++ks2) {
                const int ks = src * 2 + ks2;
                bf8 Bh[2][2], Bl[2][2];
#pragma unroll
                for (int mat = 0; mat < 2; ++mat)
#pragma unroll
                    for (int t = 0; t < 2; ++t) {
                        int pair = (ks * 2 + mat) * 2 + t;
                        Bh[mat][t] = frag[(pair*2+0)*64 + lane];
                        Bl[mat][t] = frag[(pair*2+1)*64 + lane];
                    }
#pragma unroll
                for (int s = 0; s < 2; ++s) {
                    const int slot = 2 * p + s;
                    const int tile = w + 4 * s + 8 * p;
                    const int lr = tile * 16 + n16 - 128 * p;
                    const float* ap = (const float*)sBuf + lr * 49 + ks2 * 32 + kq * 8;
                    float a[8];
#pragma unroll
                    for (int j = 0; j < 8; ++j) a[j] = ap[j];
                    bf8 Ah, Al;
                    cvt_split8(a, Ah, Al);
#pragma unroll
                    for (int t = 0; t < 2; ++t) {
                        accw[t][slot] = mfma16(Ah, Bh[0][t], accw[t][slot]);
                        accw[t][slot] = mfma16(Al, Bh[0][t], accw[t][slot]);
                        accw[t][slot] = mfma16(Ah, Bl[0][t], accw[t][slot]);
                        accb[t][slot] = mfma16(Ah, Bh[1][t], accb[t][slot]);
                        accb[t][slot] = mfma16(Al, Bh[1][t], accb[t][slot]);
                        accb[t][slot] = mfma16(Ah, Bl[1][t], accb[t][slot]);
                    }
                }
            }
        }
    }

    __syncthreads();    // staging reads done; reuse sBuf as act scratch

    // blend + relu -> packed bf16 act rows [64][34] per wave
    u32* actB = sBuf + w * 2176;
#pragma unroll
    for (int slot = 0; slot < 4; ++slot) {
        const int tile = w + 4 * (slot & 1) + 8 * (slot >> 1);
#pragma unroll
        for (int r = 0; r < 4; ++r) {
            long long sp = G + tile * 16 + kq * 4 + r;
            if (sp > (long long)B - 1) sp = B - 1;
            float pvv = pov[sp];
            int row = slot * 16 + kq * 4 + r;
            float w0 = accw[0][slot][r], b0_ = accb[0][slot][r];
            float w1 = accw[1][slot][r], b1_ = accb[1][slot][r];
            float d0 = w0 - b0_, d1 = w1 - b1_;
            float e00 = fmaxf(fmaf(pvv, d0, b0_), 0.f);   // col n16
            float e01 = fmaxf(fmaf(pvv, d1, b1_), 0.f);   // col 16+n16
            float e10 = fmaxf(w0 - pvv * d0, 0.f);        // col 32+n16
            float e11 = fmaxf(w1 - pvv * d1, 0.f);        // col 48+n16
            actB[row * 34 + n16]      = bf16_rne(e00) | (bf16_rne(e01) << 16);
            actB[row * 34 + 16 + n16] = bf16_rne(e10) | (bf16_rne(e11) << 16);
        }
    }

    // L0: x0 = relu(base @ W0^T + b0)
    f4 acc0[2][4];
    {
        float c0 = b0v[n16], c1 = b0v[16+n16];
#pragma unroll
        for (int s = 0; s < 4; ++s) { acc0[0][s] = {c0,c0,c0,c0}; acc0[1][s] = {c1,c1,c1,c1}; }
    }
#pragma unroll
    for (int ks2 = 0; ks2 < 2; ++ks2) {
        bf8 Bh[2], Bl[2];
#pragma unroll
        for (int t = 0; t < 2; ++t) {
            int pair = 16 + ks2 * 2 + t;
            Bh[t] = frag[(pair*2+0)*64 + lane];
            Bl[t] = frag[(pair*2+1)*64 + lane];
        }
#pragma unroll
        for (int slot = 0; slot < 4; ++slot) {
            const u32* ap = actB + (slot * 16 + n16) * 34 + ks2 * 16 + kq * 4;
            u32x2 d01 = *(const u32x2*)ap;
            u32x2 d23 = *(const u32x2*)(ap + 2);
            u32x4 dv = {d01.x, d01.y, d23.x, d23.y};
            bf8 A = __builtin_bit_cast(bf8, dv);
#pragma unroll
            for (int t = 0; t < 2; ++t) {
                acc0[t][slot] = mfma16(A, Bh[t], acc0[t][slot]);
                acc0[t][slot] = mfma16(A, Bl[t], acc0[t][slot]);
            }
        }
    }
    // relu; restage x0 (packed) for L1
#pragma unroll
    for (int slot = 0; slot < 4; ++slot)
#pragma unroll
        for (int r = 0; r < 4; ++r) {
            float v0 = fmaxf(acc0[0][slot][r], 0.f);
            float v1 = fmaxf(acc0[1][slot][r], 0.f);
            acc0[0][slot][r] = v0; acc0[1][slot][r] = v1;
            actB[(slot * 16 + kq * 4 + r) * 34 + n16] = bf16_rne(v0) | (bf16_rne(v1) << 16);
        }

    // L1: x1 = x0 @ W1^T + b1
    f4 acc1[2][4];
    {
        float c0 = b1v[n16], c1 = b1v[16+n16];
#pragma unroll
        for (int s = 0; s < 4; ++s) { acc1[0][s] = {c0,c0,c0,c0}; acc1[1][s] = {c1,c1,c1,c1}; }
    }
    {
        bf8 Bh[2], Bl[2];
#pragma unroll
        for (int t = 0; t < 2; ++t) {
            int pair = 20 + t;
            Bh[t] = frag[(pair*2+0)*64 + lane];
            Bl[t] = frag[(pair*2+1)*64 + lane];
        }
#pragma unroll
        for (int slot = 0; slot < 4; ++slot) {
            const u32* ap = actB + (slot * 16 + n16) * 34 + kq * 4;
            u32x2 d01 = *(const u32x2*)ap;
            u32x2 d23 = *(const u32x2*)(ap + 2);
            u32x4 dv = {d01.x, d01.y, d23.x, d23.y};
            bf8 A = __builtin_bit_cast(bf8, dv);
#pragma unroll
            for (int t = 0; t < 2; ++t) {
                acc1[t][slot] = mfma16(A, Bh[t], acc1[t][slot]);
                acc1[t][slot] = mfma16(A, Bl[t], acc1[t][slot]);
            }
        }
    }

    // out = x0.W2[0:32] + relu(x1).W2[32:64] + b2
    f4 w2 = *(const f4*)&((const float*)sW)[11264 + n16 * 4];
    float b2s = b2v[0];
#pragma unroll
    for (int slot = 0; slot < 4; ++slot) {
        const int tile = w + 4 * (slot & 1) + 8 * (slot >> 1);
#pragma unroll
        for (int r = 0; r < 4; ++r) {
            float v = acc0[0][slot][r] * w2.x + acc0[1][slot][r] * w2.y
                    + fmaxf(acc1[0][slot][r], 0.f) * w2.z
                    + fmaxf(acc1[1][slot][r], 0.f) * w2.w;
            v += __shfl_xor(v, 1);
            v += __shfl_xor(v, 2);
            v += __shfl_xor(v, 4);
            v += __shfl_xor(v, 8);
            long long so = G + tile * 16 + kq * 4 + r;
            if (n16 == 0 && so < B) out[so] = v + b2s;
        }
    }
}

extern "C" void kernel_launch(void* const* d_in, const int* in_sizes, int n_in,
                              void* d_out, int out_size, void* d_ws, size_t ws_size,
                              hipStream_t stream)
{
    const float* pov   = (const float*)d_in[0];
    const float* white = (const float*)d_in[1];
    const float* black = (const float*)d_in[2];
    const float* Ww = (const float*)d_in[3];
    const float* bw = (const float*)d_in[4];
    const float* Wb = (const float*)d_in[5];
    const float* bb = (const float*)d_in[6];
    const float* W0 = (const float*)d_in[7];
    const float* b0 = (const float*)d_in[8];
    const float* W1 = (const float*)d_in[9];
    const float* b1 = (const float*)d_in[10];
    const float* W2 = (const float*)d_in[11];
    const float* b2 = (const float*)d_in[12];
    float* out = (float*)d_out;

    const int B = in_sizes[0];
    u32* ws = (u32*)d_ws;

    hipLaunchKernelGGL(nnue_prep, dim3(23), dim3(256), 0, stream,
                       Ww, Wb, W0, W1, W2, ws);
    hipLaunchKernelGGL(nnue_main, dim3((B + 255) / 256), dim3(TPB), 0, stream,
                       pov, white, black, bw, bb, b0, b1, b2, ws, out, B);
}